// Round 6
// baseline (2629.924 us; speedup 1.0000x reference)
//
#include <hip/hip_runtime.h>
#include <cfloat>
#include <stdint.h>

// z: [32768, 32] fp32 rows; emb: [8192, 32] fp32 codes.
// Outputs (fp32, concat): quantized[1048576] | vq_loss | commit_loss | idx[32768]
//
// R6: single fused sweep. Per block: 64 rows x all 8192 codes.
//  - eh (bf16 emb) staged through LDS, double-buffered, 128-code chunks
//  - bf16 MFMA dots; per-row running threshold th = runmax - EPS
//  - candidates (codes with dot~ >= th) collected in LDS (~22/row expected)
//  - in-block exact fp32 re-check (bit-identical to the R2..R5-passing chain)
//  - in-block gather + losses. Exactness guaranteed; EPS margin 2x the worst
//    bf16+grid error bound (~4.6e-5).
#define NROW   32768
#define KCODES 8192
#define CDIM   32
#define OUT_Q    0
#define OUT_LOSS 1048576
#define OUT_IDX  1048578
#define EPS      1e-4f
#define MAXCAND  56
#define RB       64                 // rows per block
#define HALFK    (KCODES / 2)       // each wave-pair covers one half
#define CHUNK    128                // codes per chunk per half (8 KB)
#define NITER    (HALFK / CHUNK)    // 32

typedef short bf8_t __attribute__((ext_vector_type(8)));   // 8 bf16
typedef float f32x4 __attribute__((ext_vector_type(4)));

__device__ __forceinline__ unsigned short f2bf(float f) {  // RNE float->bf16
  unsigned int u = __float_as_uint(f);
  return (unsigned short)((u + 0x7FFFu + ((u >> 16) & 1u)) >> 16);
}

// ---------------------------------------------------------------------------
// Prep: zh/eh bf16 copies, enorm (R5-identical chain), zero losses.
// ---------------------------------------------------------------------------
__global__ __launch_bounds__(256) void vq_prep(
    const float* __restrict__ z, const float* __restrict__ emb,
    unsigned short* __restrict__ zh, unsigned short* __restrict__ eh,
    float* __restrict__ enorm, float* __restrict__ out) {
  const int t = blockIdx.x * 256 + threadIdx.x;  // 0..32767
  {
    const float4* z4 = (const float4*)(z + (size_t)t * CDIM);
    unsigned int w[16];
#pragma unroll
    for (int j = 0; j < 8; ++j) {
      float4 v = z4[j];
      w[2 * j]     = (unsigned int)f2bf(v.x) | ((unsigned int)f2bf(v.y) << 16);
      w[2 * j + 1] = (unsigned int)f2bf(v.z) | ((unsigned int)f2bf(v.w) << 16);
    }
    uint4* o = (uint4*)(zh + (size_t)t * CDIM);
#pragma unroll
    for (int j = 0; j < 4; ++j)
      o[j] = make_uint4(w[4 * j], w[4 * j + 1], w[4 * j + 2], w[4 * j + 3]);
  }
  if (t < KCODES) {
    const float4* e4 = (const float4*)(emb + (size_t)t * CDIM);
    float s = 0.f;
    unsigned int w[16];
#pragma unroll
    for (int j = 0; j < 8; ++j) {
      float4 v = e4[j];
      s += v.x * v.x + v.y * v.y + v.z * v.z + v.w * v.w;  // exact R5 chain
      w[2 * j]     = (unsigned int)f2bf(v.x) | ((unsigned int)f2bf(v.y) << 16);
      w[2 * j + 1] = (unsigned int)f2bf(v.z) | ((unsigned int)f2bf(v.w) << 16);
    }
    enorm[t] = s;
    uint4* o = (uint4*)(eh + (size_t)t * CDIM);
#pragma unroll
    for (int j = 0; j < 4; ++j)
      o[j] = make_uint4(w[4 * j], w[4 * j + 1], w[4 * j + 2], w[4 * j + 3]);
  }
  if (t < 2) out[OUT_LOSS + t] = 0.f;
}

// ---------------------------------------------------------------------------
// Fused sweep + finalize. grid = NROW/RB = 512 blocks x 256 threads (4 waves).
// Wave wid: row-group (wid&1)*32, code-half (wid>>1)*4096.
// ---------------------------------------------------------------------------
__global__ __launch_bounds__(256, 2) void vq_sweep(
    const float* __restrict__ z, const float* __restrict__ emb,
    const unsigned short* __restrict__ zh, const unsigned short* __restrict__ eh,
    const float* __restrict__ enorm, float* __restrict__ out) {
  __shared__ float4 ebuf[2][2][CHUNK * 4];   // [parity][half][...]  32 KB
  __shared__ int s_cnt[RB];
  __shared__ int s_cand[RB * MAXCAND];       // 14 KB
  __shared__ int s_bidx[RB];
  __shared__ float s_loss[4];

  const int tid = threadIdx.x;
  const int wid = tid >> 6, lane = tid & 63;
  const int quad = lane >> 4, col = lane & 15;
  const int rg = wid & 1;       // row group within block
  const int h  = wid >> 1;      // code half
  const int rbase = blockIdx.x * RB;

  if (tid < RB) s_cnt[tid] = 0;

  // A-fragments: A[m=col][k=quad*8+j] for 32 rows (two 16-row frags).
  const int arow = rbase + rg * 32 + col;
  bf8_t a0 = *(const bf8_t*)(zh + (size_t)arow * CDIM + quad * 8);
  bf8_t a1 = *(const bf8_t*)(zh + (size_t)(arow + 16) * CDIM + quad * 8);

  float th0[4], th1[4];
#pragma unroll
  for (int i = 0; i < 4; ++i) { th0[i] = -FLT_MAX; th1[i] = -FLT_MAX; }

  const float4* eh4 = (const float4*)eh;
  float4 st[4];

  // stage chunk-pair 0 into parity 0
#pragma unroll
  for (int h2 = 0; h2 < 2; ++h2)
#pragma unroll
    for (int j = 0; j < 2; ++j)
      ebuf[0][h2][j * 256 + tid] =
          eh4[((size_t)h2 * HALFK) * 4 + j * 256 + tid];
  __syncthreads();

  for (int i = 0; i < NITER; ++i) {
    const int p = i & 1;
    // issue next chunk's global loads now (hidden under compute)
    if (i + 1 < NITER) {
#pragma unroll
      for (int h2 = 0; h2 < 2; ++h2)
#pragma unroll
        for (int j = 0; j < 2; ++j)
          st[h2 * 2 + j] =
              eh4[((size_t)h2 * HALFK + (size_t)(i + 1) * CHUNK) * 4 +
                  j * 256 + tid];
    }

    const float4* bb = &ebuf[p][h][0];

    if (i == 0) {  // warm-up: set th from chunk 0 (prevents cold-start flood)
#pragma unroll
      for (int t = 0; t < CHUNK / 16; ++t) {
        bf8_t b = *(const bf8_t*)(bb + t * 64 + col * 4 + quad);
        f32x4 d0 = __builtin_amdgcn_mfma_f32_16x16x32_bf16(
            a0, b, (f32x4){0.f, 0.f, 0.f, 0.f}, 0, 0, 0);
        f32x4 d1 = __builtin_amdgcn_mfma_f32_16x16x32_bf16(
            a1, b, (f32x4){0.f, 0.f, 0.f, 0.f}, 0, 0, 0);
#pragma unroll
        for (int ii = 0; ii < 4; ++ii) {
          th0[ii] = fmaxf(th0[ii], d0[ii] - EPS);
          th1[ii] = fmaxf(th1[ii], d1[ii] - EPS);
        }
      }
    }

    const int cbase = h * HALFK + i * CHUNK;
#pragma unroll 4
    for (int t = 0; t < CHUNK / 16; ++t) {
      bf8_t b = *(const bf8_t*)(bb + t * 64 + col * 4 + quad);
      f32x4 d0 = __builtin_amdgcn_mfma_f32_16x16x32_bf16(
          a0, b, (f32x4){0.f, 0.f, 0.f, 0.f}, 0, 0, 0);
      f32x4 d1 = __builtin_amdgcn_mfma_f32_16x16x32_bf16(
          a1, b, (f32x4){0.f, 0.f, 0.f, 0.f}, 0, 0, 0);
      bool c0 = d0[0] >= th0[0], c1 = d0[1] >= th0[1];
      bool c2 = d0[2] >= th0[2], c3 = d0[3] >= th0[3];
      bool c4 = d1[0] >= th1[0], c5 = d1[1] >= th1[1];
      bool c6 = d1[2] >= th1[2], c7 = d1[3] >= th1[3];
      if (c0 | c1 | c2 | c3 | c4 | c5 | c6 | c7) {  // rare
        const int code = cbase + t * 16 + col;
        const int rl = rg * 32 + quad * 4;
        if (c0) { int s = atomicAdd(&s_cnt[rl + 0], 1); if (s < MAXCAND) s_cand[(rl + 0) * MAXCAND + s] = code; }
        if (c1) { int s = atomicAdd(&s_cnt[rl + 1], 1); if (s < MAXCAND) s_cand[(rl + 1) * MAXCAND + s] = code; }
        if (c2) { int s = atomicAdd(&s_cnt[rl + 2], 1); if (s < MAXCAND) s_cand[(rl + 2) * MAXCAND + s] = code; }
        if (c3) { int s = atomicAdd(&s_cnt[rl + 3], 1); if (s < MAXCAND) s_cand[(rl + 3) * MAXCAND + s] = code; }
        if (c4) { int s = atomicAdd(&s_cnt[rl + 16], 1); if (s < MAXCAND) s_cand[(rl + 16) * MAXCAND + s] = code; }
        if (c5) { int s = atomicAdd(&s_cnt[rl + 17], 1); if (s < MAXCAND) s_cand[(rl + 17) * MAXCAND + s] = code; }
        if (c6) { int s = atomicAdd(&s_cnt[rl + 18], 1); if (s < MAXCAND) s_cand[(rl + 18) * MAXCAND + s] = code; }
        if (c7) { int s = atomicAdd(&s_cnt[rl + 19], 1); if (s < MAXCAND) s_cand[(rl + 19) * MAXCAND + s] = code; }
      }
#pragma unroll
      for (int ii = 0; ii < 4; ++ii) {
        th0[ii] = fmaxf(th0[ii], d0[ii] - EPS);
        th1[ii] = fmaxf(th1[ii], d1[ii] - EPS);
      }
    }

    if (i + 1 < NITER) {
#pragma unroll
      for (int h2 = 0; h2 < 2; ++h2)
#pragma unroll
        for (int j = 0; j < 2; ++j)
          ebuf[p ^ 1][h2][j * 256 + tid] = st[h2 * 2 + j];
    }
    __syncthreads();
  }

  // ---- in-block exact finalize: one thread per row ----
  if (tid < RB) {
    const int r = rbase + tid;
    float zr[CDIM];
    const float4* z4 = (const float4*)(z + (size_t)r * CDIM);
#pragma unroll
    for (int j = 0; j < 8; ++j) {
      float4 v = z4[j];
      zr[4 * j + 0] = v.x; zr[4 * j + 1] = v.y;
      zr[4 * j + 2] = v.z; zr[4 * j + 3] = v.w;
    }
    float znorm = 0.f;
#pragma unroll
    for (int j = 0; j < CDIM; ++j) znorm = fmaf(zr[j], zr[j], znorm);

    const int n = s_cnt[tid];
    float best = FLT_MAX;
    int bidx = KCODES;
    if (n <= MAXCAND) {
      for (int j = 0; j < n; ++j) {
        int k = s_cand[tid * MAXCAND + j];
        const float* ek = emb + (size_t)k * CDIM;
        float dot = 0.f;
#pragma unroll
        for (int q = 0; q < CDIM; ++q) dot = fmaf(zr[q], ek[q], dot);
        float s = fmaf(-2.f, dot, znorm) + enorm[k];
        if (s < best || (s == best && k < bidx)) { best = s; bidx = k; }
      }
    } else {  // safety net (never expected): exact full scan
      for (int k = 0; k < KCODES; ++k) {
        const float* ek = emb + (size_t)k * CDIM;
        float dot = 0.f;
#pragma unroll
        for (int q = 0; q < CDIM; ++q) dot = fmaf(zr[q], ek[q], dot);
        float s = fmaf(-2.f, dot, znorm) + enorm[k];
        if (s < best) { best = s; bidx = k; }
      }
    }
    s_bidx[tid] = bidx;
    out[OUT_IDX + r] = (float)bidx;
  }
  __syncthreads();

  // ---- gather + losses: all 256 threads over RB*8 float4s ----
  float lsum = 0.f;
  const float4* emb4 = (const float4*)emb;
  const float4* z4g = (const float4*)z;
  float4* o4 = (float4*)(out + OUT_Q);
#pragma unroll
  for (int i2 = 0; i2 < (RB * 8) / 256; ++i2) {  // 2 iters
    const int i = i2 * 256 + tid;
    const int row = i >> 3, j = i & 7;
    const int b = s_bidx[row];
    float4 q = emb4[(size_t)b * 8 + j];
    float4 zz = z4g[((size_t)rbase + row) * 8 + j];
    float dx = zz.x - q.x, dy = zz.y - q.y, dz = zz.z - q.z, dw = zz.w - q.w;
    lsum += dx * dx + dy * dy + dz * dz + dw * dw;
    o4[((size_t)rbase + row) * 8 + j] = q;
  }
#pragma unroll
  for (int off = 32; off > 0; off >>= 1) lsum += __shfl_down(lsum, off, 64);
  if (lane == 0) s_loss[wid] = lsum;
  __syncthreads();
  if (tid == 0) {
    float v = (s_loss[0] + s_loss[1] + s_loss[2] + s_loss[3]) *
              (1.0f / (float)(NROW * CDIM));
    atomicAdd(out + OUT_LOSS + 0, v);
    atomicAdd(out + OUT_LOSS + 1, v);
  }
}

// ---------------------------------------------------------------------------
extern "C" void kernel_launch(void* const* d_in, const int* in_sizes, int n_in,
                              void* d_out, int out_size, void* d_ws,
                              size_t ws_size, hipStream_t stream) {
  const float* z = (const float*)d_in[0];
  const float* emb = (const float*)d_in[1];
  float* out = (float*)d_out;

  // ws: enorm 32KB | zh 2MB | eh 512KB
  float* enorm = (float*)d_ws;
  unsigned short* zh = (unsigned short*)(enorm + KCODES);
  unsigned short* eh = zh + (size_t)NROW * CDIM;

  vq_prep<<<NROW / 256, 256, 0, stream>>>(z, emb, zh, eh, enorm, out);
  vq_sweep<<<NROW / RB, 256, 0, stream>>>(z, emb, zh, eh, enorm, out);
}

// Round 7
// 2240.295 us; speedup vs baseline: 1.1739x; 1.1739x over previous
//
#include <hip/hip_runtime.h>
#include <cfloat>
#include <stdint.h>

// z: [32768, 32] fp32 rows; emb: [8192, 32] fp32 codes.
// Outputs (fp32, concat): quantized[1048576] | vq_loss | commit_loss | idx[32768]
//
// R7: fused bf16-MFMA filter + exact fp32 re-check, one 512-thread block per
// 128 rows (grid=256 = 1 block/CU). emb (bf16) streamed through LDS in
// 256-code chunks, double-buffered, fragments stored in READ-LANE ORDER
// (ds_read_b128 on consecutive lanes = conflict-free; R6's 64B-stride read
// pattern caused 4.4M bank-conflict cycles). Per-row running threshold is
// butterfly-shared across the row's 16 lanes each chunk (R6's per-lane
// threshold caused ~100 emits/row -> fallback scans -> 2.6ms).
#define NROW   32768
#define KCODES 8192
#define CDIM   32
#define OUT_Q    0
#define OUT_LOSS 1048576
#define OUT_IDX  1048578
#define EPS      1e-4f    // > 2*bf16 dot error (~4.6e-5) + enorm/grid slack
#define MAXCAND  32
#define RB       128      // rows per block
#define CHUNK    256      // codes per staged chunk (16 KB)
#define NIT      (KCODES / CHUNK)  // 32

typedef short bf8_t __attribute__((ext_vector_type(8)));   // 8 bf16
typedef float f32x4 __attribute__((ext_vector_type(4)));

__device__ __forceinline__ unsigned short f2bf(float f) {  // RNE float->bf16
  unsigned int u = __float_as_uint(f);
  return (unsigned short)((u + 0x7FFFu + ((u >> 16) & 1u)) >> 16);
}

// ---------------------------------------------------------------------------
// Prep: eh = bf16(emb); enorm[k] = ||emb_k||^2 (bit-identical R2..R6 chain);
// zero the loss slots. grid = KCODES/256 = 32 blocks.
// ---------------------------------------------------------------------------
__global__ __launch_bounds__(256) void vq_prep(
    const float* __restrict__ emb, unsigned short* __restrict__ eh,
    float* __restrict__ enorm, float* __restrict__ out) {
  const int k = blockIdx.x * 256 + threadIdx.x;
  const float4* e4 = (const float4*)(emb + (size_t)k * CDIM);
  float s = 0.f;
  unsigned int w[16];
#pragma unroll
  for (int j = 0; j < 8; ++j) {
    float4 v = e4[j];
    s += v.x * v.x + v.y * v.y + v.z * v.z + v.w * v.w;
    w[2 * j]     = (unsigned int)f2bf(v.x) | ((unsigned int)f2bf(v.y) << 16);
    w[2 * j + 1] = (unsigned int)f2bf(v.z) | ((unsigned int)f2bf(v.w) << 16);
  }
  enorm[k] = s;
  uint4* o = (uint4*)(eh + (size_t)k * CDIM);
#pragma unroll
  for (int j = 0; j < 4; ++j)
    o[j] = make_uint4(w[4 * j], w[4 * j + 1], w[4 * j + 2], w[4 * j + 3]);
  if (blockIdx.x == 0 && threadIdx.x < 2) out[OUT_LOSS + threadIdx.x] = 0.f;
}

// ---------------------------------------------------------------------------
// Fused sweep + exact finalize. grid = NROW/RB = 256 blocks x 512 threads
// (8 waves x 16 rows). Every wave sweeps all 8192 codes.
// ---------------------------------------------------------------------------
__global__ __launch_bounds__(512, 2) void vq_sweep(
    const float* __restrict__ z, const float* __restrict__ emb,
    const unsigned short* __restrict__ eh, const float* __restrict__ enorm,
    float* __restrict__ out) {
  __shared__ float4 ebuf[2][CHUNK * 4];   // 32 KB, read-lane-order fragments
  __shared__ int s_cnt[RB];
  __shared__ int s_cand[RB * MAXCAND];    // 16 KB
  __shared__ int s_bidx[RB];
  __shared__ float s_loss[8];

  const int tid = threadIdx.x;
  const int wid = tid >> 6, lane = tid & 63;
  const int quad = lane >> 4, col = lane & 15;
  const int rbase = blockIdx.x * RB;

  if (tid < RB) s_cnt[tid] = 0;

  // A-fragment: A[m=col][k=quad*8+j] = bf16(z[rbase + wid*16 + col][k])
  bf8_t a0;
  {
    const float4* zz =
        (const float4*)(z + (size_t)(rbase + wid * 16 + col) * CDIM + quad * 8);
    float4 v0 = zz[0], v1 = zz[1];
    a0[0] = (short)f2bf(v0.x); a0[1] = (short)f2bf(v0.y);
    a0[2] = (short)f2bf(v0.z); a0[3] = (short)f2bf(v0.w);
    a0[4] = (short)f2bf(v1.x); a0[5] = (short)f2bf(v1.y);
    a0[6] = (short)f2bf(v1.z); a0[7] = (short)f2bf(v1.w);
  }

  const float4* eh4 = (const float4*)eh;

  // Stage chunk 0. Global float4 i (within chunk) -> lds slot
  // (i&~63) + (i&3)*16 + ((i>>2)&15): tile t=i>>6, B-frag lane quad=i&3,
  // col=(i>>2)&15 -> reads at [t*64 + lane] are consecutive-lane b128.
#pragma unroll
  for (int s = 0; s < 2; ++s) {
    int i = tid + s * 512;
    ebuf[0][(i & ~63) + (i & 3) * 16 + ((i >> 2) & 15)] = eh4[i];
  }
  __syncthreads();

  float rm[4] = {-FLT_MAX, -FLT_MAX, -FLT_MAX, -FLT_MAX};

  // Warm-up: chunk 0 max-only (prevents cold-start emit flood).
#pragma unroll 4
  for (int t = 0; t < CHUNK / 16; ++t) {
    bf8_t b = *(const bf8_t*)&ebuf[0][t * 64 + lane];
    f32x4 d = __builtin_amdgcn_mfma_f32_16x16x32_bf16(
        a0, b, (f32x4){0.f, 0.f, 0.f, 0.f}, 0, 0, 0);
#pragma unroll
    for (int i = 0; i < 4; ++i) rm[i] = fmaxf(rm[i], d[i]);
  }
  float th[4];
#pragma unroll
  for (int off = 1; off < 16; off <<= 1)
#pragma unroll
    for (int i = 0; i < 4; ++i) rm[i] = fmaxf(rm[i], __shfl_xor(rm[i], off, 64));
#pragma unroll
  for (int i = 0; i < 4; ++i) th[i] = rm[i] - EPS;

  float4 st[2];
  for (int ic = 0; ic < NIT; ++ic) {
    const int p = ic & 1;
    if (ic + 1 < NIT) {  // prefetch next chunk into regs (hidden under MFMA)
      const int gb = (ic + 1) * CHUNK * 4;
#pragma unroll
      for (int s = 0; s < 2; ++s) st[s] = eh4[gb + tid + s * 512];
    }

    const int cbase = ic * CHUNK;
#pragma unroll 4
    for (int t = 0; t < CHUNK / 16; ++t) {
      bf8_t b = *(const bf8_t*)&ebuf[p][t * 64 + lane];
      f32x4 d = __builtin_amdgcn_mfma_f32_16x16x32_bf16(
          a0, b, (f32x4){0.f, 0.f, 0.f, 0.f}, 0, 0, 0);
      bool c0 = d[0] >= th[0], c1 = d[1] >= th[1];
      bool c2 = d[2] >= th[2], c3 = d[3] >= th[3];
      if (c0 | c1 | c2 | c3) {  // rare: ~7-9 hits/row over the whole sweep
        const int code = cbase + t * 16 + col;
        const int rl = wid * 16 + quad * 4;
        if (c0) { int s = atomicAdd(&s_cnt[rl + 0], 1); if (s < MAXCAND) s_cand[(rl + 0) * MAXCAND + s] = code; }
        if (c1) { int s = atomicAdd(&s_cnt[rl + 1], 1); if (s < MAXCAND) s_cand[(rl + 1) * MAXCAND + s] = code; }
        if (c2) { int s = atomicAdd(&s_cnt[rl + 2], 1); if (s < MAXCAND) s_cand[(rl + 2) * MAXCAND + s] = code; }
        if (c3) { int s = atomicAdd(&s_cnt[rl + 3], 1); if (s < MAXCAND) s_cand[(rl + 3) * MAXCAND + s] = code; }
      }
#pragma unroll
      for (int i = 0; i < 4; ++i) rm[i] = fmaxf(rm[i], d[i]);
    }

    if (ic + 1 < NIT) {
#pragma unroll
      for (int s = 0; s < 2; ++s) {
        int i = tid + s * 512;
        ebuf[p ^ 1][(i & ~63) + (i & 3) * 16 + ((i >> 2) & 15)] = st[s];
      }
    }
    __syncthreads();

    // share per-row running max across the row's 16 lanes; refresh threshold
#pragma unroll
    for (int off = 1; off < 16; off <<= 1)
#pragma unroll
      for (int i = 0; i < 4; ++i)
        rm[i] = fmaxf(rm[i], __shfl_xor(rm[i], off, 64));
#pragma unroll
    for (int i = 0; i < 4; ++i) th[i] = rm[i] - EPS;
  }

  // ---- exact finalize: one thread per row, R2..R6 bit-identical chain ----
  if (tid < RB) {
    const int r = rbase + tid;
    float zr[CDIM];
    const float4* z4 = (const float4*)(z + (size_t)r * CDIM);
#pragma unroll
    for (int j = 0; j < 8; ++j) {
      float4 v = z4[j];
      zr[4 * j + 0] = v.x; zr[4 * j + 1] = v.y;
      zr[4 * j + 2] = v.z; zr[4 * j + 3] = v.w;
    }
    float znorm = 0.f;
#pragma unroll
    for (int j = 0; j < CDIM; ++j) znorm = fmaf(zr[j], zr[j], znorm);

    const int n = s_cnt[tid];
    float best = FLT_MAX;
    int bidx = KCODES;
    if (n <= MAXCAND) {
      for (int j = 0; j < n; ++j) {
        int k = s_cand[tid * MAXCAND + j];
        const float4* ek4 = (const float4*)(emb + (size_t)k * CDIM);
        float dot = 0.f;
#pragma unroll
        for (int q = 0; q < 8; ++q) {  // ascending order preserved
          float4 e = ek4[q];
          dot = fmaf(zr[4 * q + 0], e.x, dot);
          dot = fmaf(zr[4 * q + 1], e.y, dot);
          dot = fmaf(zr[4 * q + 2], e.z, dot);
          dot = fmaf(zr[4 * q + 3], e.w, dot);
        }
        float s = fmaf(-2.f, dot, znorm) + enorm[k];
        if (s < best || (s == best && k < bidx)) { best = s; bidx = k; }
      }
    } else {  // safety net (P ~ 0): exact full scan, ascending k
      for (int k = 0; k < KCODES; ++k) {
        const float* ek = emb + (size_t)k * CDIM;
        float dot = 0.f;
#pragma unroll
        for (int q = 0; q < CDIM; ++q) dot = fmaf(zr[q], ek[q], dot);
        float s = fmaf(-2.f, dot, znorm) + enorm[k];
        if (s < best) { best = s; bidx = k; }
      }
    }
    s_bidx[tid] = bidx;
    out[OUT_IDX + r] = (float)bidx;
  }
  __syncthreads();

  // ---- gather + losses: 512 threads over RB*8 = 1024 float4s ----
  float lsum = 0.f;
  const float4* emb4 = (const float4*)emb;
  const float4* z4g = (const float4*)z;
  float4* o4 = (float4*)(out + OUT_Q);
#pragma unroll
  for (int i2 = 0; i2 < (RB * 8) / 512; ++i2) {  // 2 iters
    const int i = i2 * 512 + tid;
    const int row = i >> 3, j = i & 7;
    const int b = s_bidx[row];
    float4 q = emb4[(size_t)b * 8 + j];
    float4 zz = z4g[((size_t)rbase + row) * 8 + j];
    float dx = zz.x - q.x, dy = zz.y - q.y, dz = zz.z - q.z, dw = zz.w - q.w;
    lsum += dx * dx + dy * dy + dz * dz + dw * dw;
    o4[((size_t)rbase + row) * 8 + j] = q;
  }
#pragma unroll
  for (int off = 32; off > 0; off >>= 1) lsum += __shfl_down(lsum, off, 64);
  if (lane == 0) s_loss[wid] = lsum;
  __syncthreads();
  if (tid == 0) {
    float v = 0.f;
#pragma unroll
    for (int w = 0; w < 8; ++w) v += s_loss[w];
    v *= (1.0f / (float)(NROW * CDIM));
    atomicAdd(out + OUT_LOSS + 0, v);
    atomicAdd(out + OUT_LOSS + 1, v);
  }
}

// ---------------------------------------------------------------------------
extern "C" void kernel_launch(void* const* d_in, const int* in_sizes, int n_in,
                              void* d_out, int out_size, void* d_ws,
                              size_t ws_size, hipStream_t stream) {
  const float* z = (const float*)d_in[0];
  const float* emb = (const float*)d_in[1];
  float* out = (float*)d_out;

  // ws: enorm 32KB | eh 512KB
  float* enorm = (float*)d_ws;
  unsigned short* eh = (unsigned short*)(enorm + KCODES);

  vq_prep<<<KCODES / 256, 256, 0, stream>>>(emb, eh, enorm, out);
  vq_sweep<<<NROW / RB, 512, 0, stream>>>(z, emb, eh, enorm, out);
}

// Round 8
// 228.414 us; speedup vs baseline: 11.5138x; 9.8080x over previous
//
#include <hip/hip_runtime.h>
#include <cfloat>
#include <stdint.h>

// z: [32768, 32] fp32 rows; emb: [8192, 32] fp32 codes.
// Outputs (fp32, concat): quantized[1048576] | vq_loss | commit_loss | idx[32768]
//
// R8: fused bf16-MFMA filter + exact fp32 re-check.
//  - 256 blocks x 256 threads (4 waves); block owns 128 rows x all 8192 codes
//  - each wave: 32 rows (2 A-frags), 2 MFMAs per staged B-read
//  - emb(bf16) via LDS, double-buffered 512-code chunks; global-side permuted
//    staging -> sequential LDS writes (R7's permuted writes = 3.5M conflicts)
//  - per-row running threshold (butterfly-shared each chunk), EPS=6e-5,
//    MAXCAND=64 (R7: stale-threshold emits ~20/row vs MAXCAND=32 -> ~77 rows
//    hit a 1ms/row per-thread fallback scan = the whole 2.2ms)
//  - overflow fallback is now wave-cooperative (exact, ~8us) - insurance only
#define NROW   32768
#define KCODES 8192
#define CDIM   32
#define OUT_Q    0
#define OUT_LOSS 1048576
#define OUT_IDX  1048578
#define EPS      6e-5f    // >= 2.5x worst-row bf16+grid error bound (~2.4e-5)
#define MAXCAND  64
#define RB       128                 // rows per block
#define CHUNK    512                 // codes per staged chunk (32 KB)
#define NIT      (KCODES / CHUNK)    // 16

typedef short bf8_t __attribute__((ext_vector_type(8)));   // 8 bf16
typedef float f32x4 __attribute__((ext_vector_type(4)));

__device__ __forceinline__ unsigned short f2bf(float f) {  // RNE float->bf16
  unsigned int u = __float_as_uint(f);
  return (unsigned short)((u + 0x7FFFu + ((u >> 16) & 1u)) >> 16);
}

// ---------------------------------------------------------------------------
// Prep: eh = bf16(emb); enorm[k] = ||emb_k||^2 (bit-identical R2..R7 chain);
// zero loss slots. grid = 32 blocks.
// ---------------------------------------------------------------------------
__global__ __launch_bounds__(256) void vq_prep(
    const float* __restrict__ emb, unsigned short* __restrict__ eh,
    float* __restrict__ enorm, float* __restrict__ out) {
  const int k = blockIdx.x * 256 + threadIdx.x;
  const float4* e4 = (const float4*)(emb + (size_t)k * CDIM);
  float s = 0.f;
  unsigned int w[16];
#pragma unroll
  for (int j = 0; j < 8; ++j) {
    float4 v = e4[j];
    s += v.x * v.x + v.y * v.y + v.z * v.z + v.w * v.w;
    w[2 * j]     = (unsigned int)f2bf(v.x) | ((unsigned int)f2bf(v.y) << 16);
    w[2 * j + 1] = (unsigned int)f2bf(v.z) | ((unsigned int)f2bf(v.w) << 16);
  }
  enorm[k] = s;
  uint4* o = (uint4*)(eh + (size_t)k * CDIM);
#pragma unroll
  for (int j = 0; j < 4; ++j)
    o[j] = make_uint4(w[4 * j], w[4 * j + 1], w[4 * j + 2], w[4 * j + 3]);
  if (blockIdx.x == 0 && threadIdx.x < 2) out[OUT_LOSS + threadIdx.x] = 0.f;
}

// ---------------------------------------------------------------------------
// Fused sweep + exact finalize. grid = NROW/RB = 256 blocks x 256 threads.
// Wave wid owns rows rbase + wid*32 .. +32.
// ---------------------------------------------------------------------------
__global__ __launch_bounds__(256, 1) void vq_sweep(
    const float* __restrict__ z, const float* __restrict__ emb,
    const unsigned short* __restrict__ eh, const float* __restrict__ enorm,
    float* __restrict__ out) {
  __shared__ float4 ebuf[2][CHUNK * 4];   // 64 KB, fragment-ordered
  __shared__ int s_cnt[RB];
  __shared__ int s_cand[RB * MAXCAND];    // 32 KB
  __shared__ int s_bidx[RB];
  __shared__ int s_ovf[RB];
  __shared__ int s_ovfn;
  __shared__ float s_loss[4];

  const int tid = threadIdx.x;
  const int wid = tid >> 6, lane = tid & 63;
  const int quad = lane >> 4, col = lane & 15;
  const int rbase = blockIdx.x * RB;

  if (tid < RB) s_cnt[tid] = 0;
  if (tid == 255) s_ovfn = 0;

  // A-fragments: A[m=col][k=quad*8+j] for rows wid*32+col and wid*32+16+col.
  bf8_t a0, a1;
  {
    const float4* zz = (const float4*)(
        z + (size_t)(rbase + wid * 32 + col) * CDIM + quad * 8);
    float4 v0 = zz[0], v1 = zz[1];
    a0[0] = (short)f2bf(v0.x); a0[1] = (short)f2bf(v0.y);
    a0[2] = (short)f2bf(v0.z); a0[3] = (short)f2bf(v0.w);
    a0[4] = (short)f2bf(v1.x); a0[5] = (short)f2bf(v1.y);
    a0[6] = (short)f2bf(v1.z); a0[7] = (short)f2bf(v1.w);
    const float4* zy = (const float4*)(
        z + (size_t)(rbase + wid * 32 + 16 + col) * CDIM + quad * 8);
    float4 w0 = zy[0], w1 = zy[1];
    a1[0] = (short)f2bf(w0.x); a1[1] = (short)f2bf(w0.y);
    a1[2] = (short)f2bf(w0.z); a1[3] = (short)f2bf(w0.w);
    a1[4] = (short)f2bf(w1.x); a1[5] = (short)f2bf(w1.y);
    a1[6] = (short)f2bf(w1.z); a1[7] = (short)f2bf(w1.w);
  }

  const float4* eh4 = (const float4*)eh;
  // Global-side permutation: LDS slot i holds global f4
  //   g(i) = (i&~63) + ((i&15)<<2) + ((i>>4)&3)
  // so the hot read ebuf[t*64 + lane] (consecutive lanes, b128) delivers
  // B[k=quad*8..][n=col] for code t*16+col. Permutation stays inside a 1KB
  // segment -> global loads still fully coalesced; LDS writes sequential.
#pragma unroll
  for (int s = 0; s < (CHUNK * 4) / 256; ++s) {  // 8
    int i = tid + s * 256;
    int g = (i & ~63) + ((i & 15) << 2) + ((i >> 4) & 3);
    ebuf[0][i] = eh4[g];
  }
  __syncthreads();

  float rm0[4] = {-FLT_MAX, -FLT_MAX, -FLT_MAX, -FLT_MAX};
  float rm1[4] = {-FLT_MAX, -FLT_MAX, -FLT_MAX, -FLT_MAX};

  // Warm-up: chunk 0, max only (prevents cold-start emit flood).
#pragma unroll 4
  for (int t = 0; t < CHUNK / 16; ++t) {
    bf8_t b = *(const bf8_t*)&ebuf[0][t * 64 + lane];
    f32x4 d0 = __builtin_amdgcn_mfma_f32_16x16x32_bf16(
        a0, b, (f32x4){0.f, 0.f, 0.f, 0.f}, 0, 0, 0);
    f32x4 d1 = __builtin_amdgcn_mfma_f32_16x16x32_bf16(
        a1, b, (f32x4){0.f, 0.f, 0.f, 0.f}, 0, 0, 0);
#pragma unroll
    for (int i = 0; i < 4; ++i) {
      rm0[i] = fmaxf(rm0[i], d0[i]);
      rm1[i] = fmaxf(rm1[i], d1[i]);
    }
  }
  float th0[4], th1[4];
#pragma unroll
  for (int off = 1; off < 16; off <<= 1)
#pragma unroll
    for (int i = 0; i < 4; ++i) {
      rm0[i] = fmaxf(rm0[i], __shfl_xor(rm0[i], off, 64));
      rm1[i] = fmaxf(rm1[i], __shfl_xor(rm1[i], off, 64));
    }
#pragma unroll
  for (int i = 0; i < 4; ++i) { th0[i] = rm0[i] - EPS; th1[i] = rm1[i] - EPS; }

  float4 st[8];
  for (int ic = 0; ic < NIT; ++ic) {
    const int p = ic & 1;
    if (ic + 1 < NIT) {  // prefetch next chunk (hidden under the tile loop)
      const int gb = (ic + 1) * CHUNK * 4;
#pragma unroll
      for (int s = 0; s < 8; ++s) {
        int i = tid + s * 256;
        int g = (i & ~63) + ((i & 15) << 2) + ((i >> 4) & 3);
        st[s] = eh4[gb + g];
      }
    }

    const int cbase = ic * CHUNK;
#pragma unroll 4
    for (int t = 0; t < CHUNK / 16; ++t) {
      bf8_t b = *(const bf8_t*)&ebuf[p][t * 64 + lane];
      f32x4 d0 = __builtin_amdgcn_mfma_f32_16x16x32_bf16(
          a0, b, (f32x4){0.f, 0.f, 0.f, 0.f}, 0, 0, 0);
      f32x4 d1 = __builtin_amdgcn_mfma_f32_16x16x32_bf16(
          a1, b, (f32x4){0.f, 0.f, 0.f, 0.f}, 0, 0, 0);
      bool c0 = d0[0] >= th0[0], c1 = d0[1] >= th0[1];
      bool c2 = d0[2] >= th0[2], c3 = d0[3] >= th0[3];
      bool c4 = d1[0] >= th1[0], c5 = d1[1] >= th1[1];
      bool c6 = d1[2] >= th1[2], c7 = d1[3] >= th1[3];
      if (c0 | c1 | c2 | c3 | c4 | c5 | c6 | c7) {  // rare
        const int code = cbase + t * 16 + col;
        const int rl = wid * 32 + quad * 4;
        if (c0) { int s = atomicAdd(&s_cnt[rl + 0], 1); if (s < MAXCAND) s_cand[(rl + 0) * MAXCAND + s] = code; }
        if (c1) { int s = atomicAdd(&s_cnt[rl + 1], 1); if (s < MAXCAND) s_cand[(rl + 1) * MAXCAND + s] = code; }
        if (c2) { int s = atomicAdd(&s_cnt[rl + 2], 1); if (s < MAXCAND) s_cand[(rl + 2) * MAXCAND + s] = code; }
        if (c3) { int s = atomicAdd(&s_cnt[rl + 3], 1); if (s < MAXCAND) s_cand[(rl + 3) * MAXCAND + s] = code; }
        if (c4) { int s = atomicAdd(&s_cnt[rl + 16], 1); if (s < MAXCAND) s_cand[(rl + 16) * MAXCAND + s] = code; }
        if (c5) { int s = atomicAdd(&s_cnt[rl + 17], 1); if (s < MAXCAND) s_cand[(rl + 17) * MAXCAND + s] = code; }
        if (c6) { int s = atomicAdd(&s_cnt[rl + 18], 1); if (s < MAXCAND) s_cand[(rl + 18) * MAXCAND + s] = code; }
        if (c7) { int s = atomicAdd(&s_cnt[rl + 19], 1); if (s < MAXCAND) s_cand[(rl + 19) * MAXCAND + s] = code; }
      }
#pragma unroll
      for (int i = 0; i < 4; ++i) {
        rm0[i] = fmaxf(rm0[i], d0[i]);
        rm1[i] = fmaxf(rm1[i], d1[i]);
      }
    }

    if (ic + 1 < NIT) {  // sequential LDS writes: conflict-free
#pragma unroll
      for (int s = 0; s < 8; ++s) ebuf[p ^ 1][tid + s * 256] = st[s];
    }
    __syncthreads();

    // share per-row running max across the row's 16 lanes; refresh threshold
#pragma unroll
    for (int off = 1; off < 16; off <<= 1)
#pragma unroll
      for (int i = 0; i < 4; ++i) {
        rm0[i] = fmaxf(rm0[i], __shfl_xor(rm0[i], off, 64));
        rm1[i] = fmaxf(rm1[i], __shfl_xor(rm1[i], off, 64));
      }
#pragma unroll
    for (int i = 0; i < 4; ++i) { th0[i] = rm0[i] - EPS; th1[i] = rm1[i] - EPS; }
  }

  // ---- exact finalize phase 1: one thread per row (candidate path) ----
  if (tid < RB) {
    const int r = rbase + tid;
    const int n = s_cnt[tid];
    if (n <= MAXCAND) {
      float zr[CDIM];
      const float4* z4 = (const float4*)(z + (size_t)r * CDIM);
#pragma unroll
      for (int j = 0; j < 8; ++j) {
        float4 v = z4[j];
        zr[4 * j + 0] = v.x; zr[4 * j + 1] = v.y;
        zr[4 * j + 2] = v.z; zr[4 * j + 3] = v.w;
      }
      float znorm = 0.f;
#pragma unroll
      for (int j = 0; j < CDIM; ++j) znorm = fmaf(zr[j], zr[j], znorm);

      float best = FLT_MAX;
      int bidx = KCODES;
      for (int j = 0; j < n; ++j) {
        int k = s_cand[tid * MAXCAND + j];
        const float4* ek4 = (const float4*)(emb + (size_t)k * CDIM);
        float dot = 0.f;
#pragma unroll
        for (int q = 0; q < 8; ++q) {  // ascending j: reference fmaf order
          float4 e = ek4[q];
          dot = fmaf(zr[4 * q + 0], e.x, dot);
          dot = fmaf(zr[4 * q + 1], e.y, dot);
          dot = fmaf(zr[4 * q + 2], e.z, dot);
          dot = fmaf(zr[4 * q + 3], e.w, dot);
        }
        float s = fmaf(-2.f, dot, znorm) + enorm[k];
        if (s < best || (s == best && k < bidx)) { best = s; bidx = k; }
      }
      s_bidx[tid] = bidx;
    } else {
      int o = atomicAdd(&s_ovfn, 1);  // overflow: defer to cooperative scan
      s_ovf[o] = tid;
    }
  }
  __syncthreads();

  // ---- phase 2 (insurance, P~0): wave-cooperative exact full scan ----
  const int novf = s_ovfn;
  for (int e = wid; e < novf; e += 4) {
    const int rl = s_ovf[e];
    const int r = rbase + rl;
    float zr[CDIM];
    const float4* z4 = (const float4*)(z + (size_t)r * CDIM);
#pragma unroll
    for (int j = 0; j < 8; ++j) {
      float4 v = z4[j];
      zr[4 * j + 0] = v.x; zr[4 * j + 1] = v.y;
      zr[4 * j + 2] = v.z; zr[4 * j + 3] = v.w;
    }
    float znorm = 0.f;
#pragma unroll
    for (int j = 0; j < CDIM; ++j) znorm = fmaf(zr[j], zr[j], znorm);

    float best = FLT_MAX;
    int bidx = KCODES;
    const int k0 = lane * (KCODES / 64);
    for (int k = k0; k < k0 + KCODES / 64; ++k) {  // 128 codes per lane
      const float4* ek4 = (const float4*)(emb + (size_t)k * CDIM);
      float dot = 0.f;
#pragma unroll
      for (int q = 0; q < 8; ++q) {
        float4 ev = ek4[q];
        dot = fmaf(zr[4 * q + 0], ev.x, dot);
        dot = fmaf(zr[4 * q + 1], ev.y, dot);
        dot = fmaf(zr[4 * q + 2], ev.z, dot);
        dot = fmaf(zr[4 * q + 3], ev.w, dot);
      }
      float s = fmaf(-2.f, dot, znorm) + enorm[k];
      if (s < best) { best = s; bidx = k; }
    }
    // lexicographic (s, k) min == first-index argmin; s>0 -> bits monotone
    unsigned long long key =
        ((unsigned long long)__float_as_uint(best) << 13) |
        (unsigned long long)bidx;
#pragma unroll
    for (int off = 1; off < 64; off <<= 1) {
      unsigned long long o2 = __shfl_xor(key, off, 64);
      key = o2 < key ? o2 : key;
    }
    if (lane == 0) s_bidx[rl] = (int)(key & (unsigned long long)(KCODES - 1));
  }
  __syncthreads();

  // ---- gather + idx + losses: 256 threads over RB*8 = 1024 float4s ----
  float lsum = 0.f;
  const float4* emb4 = (const float4*)emb;
  const float4* z4g = (const float4*)z;
  float4* o4 = (float4*)(out + OUT_Q);
#pragma unroll
  for (int i2 = 0; i2 < (RB * 8) / 256; ++i2) {  // 4 iters
    const int i = i2 * 256 + tid;
    const int row = i >> 3, j = i & 7;
    const int b = s_bidx[row];
    float4 q = emb4[(size_t)b * 8 + j];
    float4 zz = z4g[((size_t)rbase + row) * 8 + j];
    float dx = zz.x - q.x, dy = zz.y - q.y, dz = zz.z - q.z, dw = zz.w - q.w;
    lsum += dx * dx + dy * dy + dz * dz + dw * dw;
    o4[((size_t)rbase + row) * 8 + j] = q;
    if (j == 0) out[OUT_IDX + rbase + row] = (float)b;
  }
#pragma unroll
  for (int off = 32; off > 0; off >>= 1) lsum += __shfl_down(lsum, off, 64);
  if (lane == 0) s_loss[wid] = lsum;
  __syncthreads();
  if (tid == 0) {
    float v = (s_loss[0] + s_loss[1] + s_loss[2] + s_loss[3]) *
              (1.0f / (float)(NROW * CDIM));
    atomicAdd(out + OUT_LOSS + 0, v);
    atomicAdd(out + OUT_LOSS + 1, v);
  }
}

// ---------------------------------------------------------------------------
extern "C" void kernel_launch(void* const* d_in, const int* in_sizes, int n_in,
                              void* d_out, int out_size, void* d_ws,
                              size_t ws_size, hipStream_t stream) {
  const float* z = (const float*)d_in[0];
  const float* emb = (const float*)d_in[1];
  float* out = (float*)d_out;

  // ws: enorm 32KB | eh 512KB
  float* enorm = (float*)d_ws;
  unsigned short* eh = (unsigned short*)(enorm + KCODES);

  vq_prep<<<KCODES / 256, 256, 0, stream>>>(emb, eh, enorm, out);
  vq_sweep<<<NROW / RB, 256, 0, stream>>>(z, emb, eh, enorm, out);
}